// Round 14
// baseline (631.944 us; speedup 1.0000x reference)
//
#include <hip/hip_runtime.h>

#define DD 512
#define BB 256
#define SS 128
#define MTOT (BB*SS)
#define GROUPS 8
#define WPG 32
#define NWG (GROUPS*WPG)  // 256
#define NTHR 256
#define SLOTS (SS+1)

typedef __bf16 bf16;
typedef float f32x4 __attribute__((ext_vector_type(4)));
typedef __bf16 bf16x8 __attribute__((ext_vector_type(8)));

__device__ __forceinline__ float sigm(float z){ return 1.f/(1.f+__expf(-z)); }
__device__ __forceinline__ unsigned short b2u(bf16 v){ union{bf16 b; unsigned short u;} x; x.b=v; return x.u; }

__global__ void k_zero(int* c, int n){ for (int i=threadIdx.x; i<n; i+=NTHR) c[i]=0; }

// ---- one-shot x fp32 -> bf16 ----
__global__ __launch_bounds__(256) void k_cvtx(const float* __restrict__ X, bf16* __restrict__ Xb){
  size_t total = (size_t)MTOT*DD;
  for (size_t i = ((size_t)blockIdx.x*256 + threadIdx.x)*8; i < total; i += (size_t)gridDim.x*256*8){
    float4 a = *(const float4*)(X+i), b = *(const float4*)(X+i+4);
    bf16x8 v;
    v[0]=(bf16)a.x; v[1]=(bf16)a.y; v[2]=(bf16)a.z; v[3]=(bf16)a.w;
    v[4]=(bf16)b.x; v[5]=(bf16)b.y; v[6]=(bf16)b.z; v[7]=(bf16)b.w;
    *(bf16x8*)(Xb+i) = v;
  }
}

// Returning swap at the DEVICE coherence point (L3). R7-R13-proven.
__device__ __forceinline__ void swapG(unsigned* a, unsigned v){
  unsigned old;
  asm volatile("global_atomic_swap %0, %1, %2, off sc0 sc1" : "=v"(old) : "v"(a), "v"(v) : "memory");
}

// A-fragment loads: 16 x dwordx4 from one row, stride 64 B.
#define LDH(I,J) asm volatile("global_load_dwordx4 %0, %1, off offset:" #J " sc0 sc1" : "=&v"(av[I]) : "v"(g))
#define LDX(I,J) asm volatile("global_load_dwordx4 %0, %1, off offset:" #J : "=&v"(av[I]) : "v"(g))

// LDS (8192 B): [0,6144) Xch f32 exchange (stride-12 dwords, conflict-free)
__launch_bounds__(NTHR, 1)
__global__ void k_main(const bf16* __restrict__ xb, const float* __restrict__ h0,
                       const float* __restrict__ Wu, const float* __restrict__ Uu, const float* __restrict__ bu,
                       const float* __restrict__ Wr, const float* __restrict__ Ur, const float* __restrict__ br,
                       const float* __restrict__ Wh, const float* __restrict__ Uh, const float* __restrict__ bh,
                       bf16* hb0, bf16* hb1,
                       int* cnt, float* __restrict__ out, float* __restrict__ hlast){
  extern __shared__ char smem[];
  float* Xch = (float*)smem;

  const int tid = threadIdx.x, w = tid>>6, lane = tid&63;
  const int grp = blockIdx.x & 7, widx = blockIdx.x >> 3;   // XCD-swizzle (perf-only)
  const int m0 = grp*32, d0 = widx*16;
  int* const cbase = cnt + grp*SLOTS;
  const int mf = w&1, half = w>>1;

  // ---- weights into registers: 3 mats x 16 k-chunks (R8-R13-proven) ----
  bf16x8 bfr[3][16];
  {
    const float* mats[3];
    if (half){ mats[0]=Wu; mats[1]=Wr; mats[2]=Wh; }
    else     { mats[0]=Uu; mats[1]=Ur; mats[2]=Uh; }
    const int col = d0 + (lane&15);
    const int kr0 = (lane>>4)*8;
    #pragma unroll
    for (int g=0; g<3; ++g){
      const float* M = mats[g] + col;
      #pragma unroll
      for (int kc=0; kc<16; ++kc){
        bf16x8 v;
        #pragma unroll
        for (int j=0;j<8;j++) v[j] = (bf16)M[(size_t)(kc*32 + kr0 + j)*DD];
        bfr[g][kc] = v;
      }
    }
  }
  const int dcol = d0 + (lane&15);
  const float bu_v = bu[dcol], br_v = br[dcol], bh_v = bh[dcol];
  float hp[4];
  if (w < 2){
    #pragma unroll
    for (int j=0;j<4;j++)
      hp[j] = h0[(size_t)(m0 + mf*16 + (lane>>4)*4 + j)*DD + dcol];
  }
  // ---- init h shadow via returning swaps + slot-0 barrier (R7-R13-proven) ----
  {
    const int pm = tid>>3, pdc = tid&7;
    unsigned* pd = (unsigned*)(hb0 + (size_t)(m0+pm)*DD + d0 + pdc*2);
    const float* src = h0 + (size_t)(m0+pm)*DD + d0 + pdc*2;
    unsigned pv = (unsigned)b2u((bf16)src[0]) | ((unsigned)b2u((bf16)src[1]) << 16);
    swapG(pd, pv);
    asm volatile("s_waitcnt vmcnt(0)" ::: "memory");
  }
  __syncthreads();
  if (tid==0){
    unsigned old, v;
    asm volatile("global_atomic_add %0, %1, %2, off sc0 sc1" : "=v"(old) : "v"(cbase), "v"(1u) : "memory");
    do { __builtin_amdgcn_s_sleep(2);
         asm volatile("global_load_dword %0, %1, off sc0 sc1\n\ts_waitcnt vmcnt(0)" : "=v"(v) : "v"(cbase) : "memory");
    } while (v < WPG);
  }
  __syncthreads();

  // per-lane A-source rows
  const int arow = mf*16 + (lane&15);
  const int coff = lane>>4;
  const bf16* const hA0 = hb0 + (size_t)(m0+arow)*DD + coff*8;
  const bf16* const hA1 = hb1 + (size_t)(m0+arow)*DD + coff*8;
  const bf16* const xA  = xb + (size_t)(m0+arow)*SS*DD + coff*8;
  // shfl-publish destinations (waves 0,1): 2 dword slots per lane
  const int rowA = mf*16 + (lane>>4)*4 + ((lane&1)<<1);
  const int cpair = d0 + ((lane&15)&14);
  unsigned* const pubA0 = (unsigned*)(hb0 + (size_t)(m0+rowA)*DD + cpair);
  unsigned* const pubA1 = (unsigned*)(hb1 + (size_t)(m0+rowA)*DD + cpair);

  bf16x8 av[16];
  if (half){   // pre-issue x A-frags for st=0
    const bf16* g = xA;
    LDX(0,0); LDX(1,64); LDX(2,128); LDX(3,192); LDX(4,256); LDX(5,320); LDX(6,384); LDX(7,448);
    LDX(8,512); LDX(9,576); LDX(10,640); LDX(11,704); LDX(12,768); LDX(13,832); LDX(14,896); LDX(15,960);
  }

  for (int st=0; st<SS; st++){
    if (!half){  // h A-frags (coherent)
      const bf16* g = (st&1)? hA1 : hA0;
      LDH(0,0); LDH(1,64); LDH(2,128); LDH(3,192); LDH(4,256); LDH(5,320); LDH(6,384); LDH(7,448);
      LDH(8,512); LDH(9,576); LDH(10,640); LDH(11,704); LDH(12,768); LDH(13,832); LDH(14,896); LDH(15,960);
    }
    asm volatile("s_waitcnt vmcnt(0)" ::: "memory");
    __builtin_amdgcn_sched_barrier(0);
    // ---- K-loop: pure-register, 48 MFMAs ----
    f32x4 acc0{}, acc1{}, acc2{};
    #pragma unroll
    for (int it=0; it<16; it++){
      acc0 = __builtin_amdgcn_mfma_f32_16x16x32_bf16(av[it], bfr[0][it], acc0, 0,0,0);
      acc1 = __builtin_amdgcn_mfma_f32_16x16x32_bf16(av[it], bfr[1][it], acc1, 0,0,0);
      acc2 = __builtin_amdgcn_mfma_f32_16x16x32_bf16(av[it], bfr[2][it], acc2, 0,0,0);
    }
    if (half){
      float* dst = Xch + (size_t)(mf*64 + lane)*12;
      *(f32x4*)(dst+0) = acc0; *(f32x4*)(dst+4) = acc1; *(f32x4*)(dst+8) = acc2;
    }
    __syncthreads();                                     // (A) Xch ready
    f32x4 hnv{};
    if (!half){
      const float* src = Xch + (size_t)(mf*64 + lane)*12;
      f32x4 p0 = *(const f32x4*)(src+0);
      f32x4 p1 = *(const f32x4*)(src+4);
      f32x4 p2 = *(const f32x4*)(src+8);
      #pragma unroll
      for (int j=0;j<4;j++){
        float u  = sigm(acc0[j] + p0[j] + bu_v);
        float rr = sigm(acc1[j] + p1[j] + br_v);
        float hh = tanhf(p2[j] + bh_v + rr*acc2[j]);
        float hn = (1.f-u)*hp[j] + u*hh;
        hp[j] = hn;
        hnv[j] = hn;
      }
    }
    if (st < SS-1){
      if (!half){
        // ---- shfl publish straight from registers (2 dwords/lane) ----
        float nb0 = __shfl_xor(hnv[0],1), nb1 = __shfl_xor(hnv[1],1);
        float nb2 = __shfl_xor(hnv[2],1), nb3 = __shfl_xor(hnv[3],1);
        unsigned vA, vB;
        if (lane&1){
          vA = (unsigned)b2u((bf16)nb2)     | ((unsigned)b2u((bf16)hnv[2])<<16);
          vB = (unsigned)b2u((bf16)nb3)     | ((unsigned)b2u((bf16)hnv[3])<<16);
        } else {
          vA = (unsigned)b2u((bf16)hnv[0])  | ((unsigned)b2u((bf16)nb0)<<16);
          vB = (unsigned)b2u((bf16)hnv[1])  | ((unsigned)b2u((bf16)nb1)<<16);
        }
        unsigned* pA = (st&1)? pubA0 : pubA1;   // write the buffer step st+1 reads
        swapG(pA, vA);
        swapG(pA + DD/2, vB);                   // row+1
        asm volatile("s_waitcnt vmcnt(0)" ::: "memory");
        int* cp = cbase + st + 1;
        if (lane==0)
          asm volatile("global_atomic_add %0, %1, off sc1" :: "v"(cp), "v"(1u) : "memory");
        unsigned v;
        do { __builtin_amdgcn_s_sleep(2);
             asm volatile("global_load_dword %0, %1, off sc0 sc1\n\ts_waitcnt vmcnt(0)" : "=v"(v) : "v"(cp) : "memory");
        } while (v < 2*WPG);
      } else {
        // ---- prefetch next x A-frags under the peers' publish/spin ----
        const bf16* g = xA + (size_t)(st+1)*DD;
        LDX(0,0); LDX(1,64); LDX(2,128); LDX(3,192); LDX(4,256); LDX(5,320); LDX(6,384); LDX(7,448);
        LDX(8,512); LDX(9,576); LDX(10,640); LDX(11,704); LDX(12,768); LDX(13,832); LDX(14,896); LDX(15,960);
      }
      __syncthreads();                                   // (B) barrier done + Xch reusable
    }
    // ---- deferred output stores (drain under next step's A-load wait) ----
    if (!half){
      int mlocal = mf*16 + (lane>>4)*4;
      #pragma unroll
      for (int j=0;j<4;j++){
        int m = m0 + mlocal + j;
        out[((size_t)m*SS + st)*DD + dcol] = hnv[j];
        if (st == SS-1) hlast[(size_t)m*DD + dcol] = hnv[j];
      }
    }
  }
}

extern "C" void kernel_launch(void* const* d_in, const int* in_sizes, int n_in,
                              void* d_out, int out_size, void* d_ws, size_t ws_size,
                              hipStream_t stream){
  const float* x   = (const float*)d_in[0];
  // d_in[1] = item (unused: softmax over length-1 axis == 1)
  const float* h0  = (const float*)d_in[2];
  const float* Wu  = (const float*)d_in[3];
  const float* Uu  = (const float*)d_in[4];
  const float* bu  = (const float*)d_in[5];
  const float* Wr  = (const float*)d_in[6];
  const float* Ur  = (const float*)d_in[7];
  const float* br  = (const float*)d_in[8];
  const float* Wh  = (const float*)d_in[9];
  const float* Uh  = (const float*)d_in[10];
  const float* bh  = (const float*)d_in[11];
  // d_in[12] = Wa (unused)
  float* out   = (float*)d_out;
  float* hlast = out + (size_t)MTOT*DD;

  char* ws = (char*)d_ws;
  bf16* xb  = (bf16*)(ws);                 // 32 MB
  bf16* hb0 = (bf16*)(ws + 0x2000000);     // 256 KB
  bf16* hb1 = (bf16*)(ws + 0x2040000);     // 256 KB
  int*  cnt = (int*)(ws + 0x2080000);      // 8*129 ints

  k_cvtx<<<dim3(2048), dim3(256), 0, stream>>>(x, xb);
  k_zero<<<dim3(1), dim3(NTHR), 0, stream>>>(cnt, GROUPS*SLOTS);
  k_main<<<dim3(NWG), dim3(NTHR), 8192, stream>>>(
      xb, h0, Wu, Uu, bu, Wr, Ur, br, Wh, Uh, bh, hb0, hb1, cnt, out, hlast);
}

// Round 15
// 548.612 us; speedup vs baseline: 1.1519x; 1.1519x over previous
//
#include <hip/hip_runtime.h>

#define DD 512
#define BB 256
#define SS 128
#define MTOT (BB*SS)
#define GROUPS 8
#define WPG 32
#define NWG (GROUPS*WPG)  // 256
#define NTHR 256
#define SLOTS (SS+1)

typedef __bf16 bf16;
typedef float f32x4 __attribute__((ext_vector_type(4)));
typedef __bf16 bf16x8 __attribute__((ext_vector_type(8)));

__device__ __forceinline__ float sigm(float z){ return 1.f/(1.f+__expf(-z)); }
__device__ __forceinline__ unsigned short b2u(bf16 v){ union{bf16 b; unsigned short u;} x; x.b=v; return x.u; }

__global__ void k_zero(int* c, int n){ for (int i=threadIdx.x; i<n; i+=NTHR) c[i]=0; }

// ---- one-shot x fp32 -> bf16 ----
__global__ __launch_bounds__(256) void k_cvtx(const float* __restrict__ X, bf16* __restrict__ Xb){
  size_t total = (size_t)MTOT*DD;
  for (size_t i = ((size_t)blockIdx.x*256 + threadIdx.x)*8; i < total; i += (size_t)gridDim.x*256*8){
    float4 a = *(const float4*)(X+i), b = *(const float4*)(X+i+4);
    bf16x8 v;
    v[0]=(bf16)a.x; v[1]=(bf16)a.y; v[2]=(bf16)a.z; v[3]=(bf16)a.w;
    v[4]=(bf16)b.x; v[5]=(bf16)b.y; v[6]=(bf16)b.z; v[7]=(bf16)b.w;
    *(bf16x8*)(Xb+i) = v;
  }
}

// Returning swap at the DEVICE coherence point (L3): vmcnt-ack of the returned
// value proves the data is physically at the shared point. R7-R13-proven.
__device__ __forceinline__ void swapG(unsigned* a, unsigned v){
  unsigned old;
  asm volatile("global_atomic_swap %0, %1, %2, off sc0 sc1" : "=v"(old) : "v"(a), "v"(v) : "memory");
}

// A-fragment loads: 16 x dwordx4 from one row, stride 64 B.
#define LDH(I,J) asm volatile("global_load_dwordx4 %0, %1, off offset:" #J " sc0 sc1" : "=&v"(av[I]) : "v"(g))
#define LDX(I,J) asm volatile("global_load_dwordx4 %0, %1, off offset:" #J : "=&v"(av[I]) : "v"(g))

// LDS (16384 B): [0,6144) Xch f32 exchange (stride-12 dwords, conflict-free);
//                [8192, 8192+1280) Hn pack tile [32][20] bf16 (stride-20, conflict-free)
__launch_bounds__(NTHR, 1)
__global__ void k_main(const bf16* __restrict__ xb, const float* __restrict__ h0,
                       const float* __restrict__ Wu, const float* __restrict__ Uu, const float* __restrict__ bu,
                       const float* __restrict__ Wr, const float* __restrict__ Ur, const float* __restrict__ br,
                       const float* __restrict__ Wh, const float* __restrict__ Uh, const float* __restrict__ bh,
                       bf16* hb0, bf16* hb1,
                       int* cnt, float* __restrict__ out, float* __restrict__ hlast){
  extern __shared__ char smem[];
  float* Xch = (float*)smem;
  bf16*  Hn  = (bf16*)(smem + 8192);

  const int tid = threadIdx.x, w = tid>>6, lane = tid&63;
  const int grp = blockIdx.x & 7, widx = blockIdx.x >> 3;   // XCD-swizzle (perf-only)
  const int m0 = grp*32, d0 = widx*16;
  int* const cbase = cnt + grp*SLOTS;
  const int mf = w&1, half = w>>1;

  // ---- weights into registers: 3 mats x 16 k-chunks (R8-R13-proven) ----
  bf16x8 bfr[3][16];
  {
    const float* mats[3];
    if (half){ mats[0]=Wu; mats[1]=Wr; mats[2]=Wh; }
    else     { mats[0]=Uu; mats[1]=Ur; mats[2]=Uh; }
    const int col = d0 + (lane&15);
    const int kr0 = (lane>>4)*8;
    #pragma unroll
    for (int g=0; g<3; ++g){
      const float* M = mats[g] + col;
      #pragma unroll
      for (int kc=0; kc<16; ++kc){
        bf16x8 v;
        #pragma unroll
        for (int j=0;j<8;j++) v[j] = (bf16)M[(size_t)(kc*32 + kr0 + j)*DD];
        bfr[g][kc] = v;
      }
    }
  }
  const int dcol = d0 + (lane&15);
  const float bu_v = bu[dcol], br_v = br[dcol], bh_v = bh[dcol];
  float hp[4];
  if (w < 2){
    #pragma unroll
    for (int j=0;j<4;j++)
      hp[j] = h0[(size_t)(m0 + mf*16 + (lane>>4)*4 + j)*DD + dcol];
  }
  // ---- init h shadow via returning swaps + slot-0 barrier (R7-R13-proven) ----
  const int pm = tid>>3, pdc = tid&7;
  unsigned* const packdst0 = (unsigned*)(hb0 + (size_t)(m0+pm)*DD + d0 + pdc*2);
  unsigned* const packdst1 = (unsigned*)(hb1 + (size_t)(m0+pm)*DD + d0 + pdc*2);
  {
    const float* src = h0 + (size_t)(m0+pm)*DD + d0 + pdc*2;
    unsigned pv = (unsigned)b2u((bf16)src[0]) | ((unsigned)b2u((bf16)src[1]) << 16);
    swapG(packdst0, pv);
    asm volatile("s_waitcnt vmcnt(0)" ::: "memory");
  }
  __syncthreads();
  if (tid==0){
    unsigned old, v;
    asm volatile("global_atomic_add %0, %1, %2, off sc0 sc1" : "=v"(old) : "v"(cbase), "v"(1u) : "memory");
    do { __builtin_amdgcn_s_sleep(2);
         asm volatile("global_load_dword %0, %1, off sc0 sc1\n\ts_waitcnt vmcnt(0)" : "=v"(v) : "v"(cbase) : "memory");
    } while (v < WPG);
  }
  __syncthreads();

  // per-lane A-source rows
  const int arow = mf*16 + (lane&15);
  const int coff = lane>>4;
  const bf16* const hA0 = hb0 + (size_t)(m0+arow)*DD + coff*8;
  const bf16* const hA1 = hb1 + (size_t)(m0+arow)*DD + coff*8;
  const bf16* const xA  = xb + (size_t)(m0+arow)*SS*DD + coff*8;

  bf16x8 av[16];
  if (half){   // pre-issue x A-frags for st=0
    const bf16* g = xA;
    LDX(0,0); LDX(1,64); LDX(2,128); LDX(3,192); LDX(4,256); LDX(5,320); LDX(6,384); LDX(7,448);
    LDX(8,512); LDX(9,576); LDX(10,640); LDX(11,704); LDX(12,768); LDX(13,832); LDX(14,896); LDX(15,960);
  }

  for (int st=0; st<SS; st++){
    if (!half){  // h A-frags (coherent)
      const bf16* g = (st&1)? hA1 : hA0;
      LDH(0,0); LDH(1,64); LDH(2,128); LDH(3,192); LDH(4,256); LDH(5,320); LDH(6,384); LDH(7,448);
      LDH(8,512); LDH(9,576); LDH(10,640); LDH(11,704); LDH(12,768); LDH(13,832); LDH(14,896); LDH(15,960);
    }
    asm volatile("s_waitcnt vmcnt(0)" ::: "memory");
    __builtin_amdgcn_sched_barrier(0);
    // ---- K-loop: pure-register, 48 MFMAs ----
    f32x4 acc0{}, acc1{}, acc2{};
    #pragma unroll
    for (int it=0; it<16; it++){
      acc0 = __builtin_amdgcn_mfma_f32_16x16x32_bf16(av[it], bfr[0][it], acc0, 0,0,0);
      acc1 = __builtin_amdgcn_mfma_f32_16x16x32_bf16(av[it], bfr[1][it], acc1, 0,0,0);
      acc2 = __builtin_amdgcn_mfma_f32_16x16x32_bf16(av[it], bfr[2][it], acc2, 0,0,0);
    }
    if (half){
      float* dst = Xch + (size_t)(mf*64 + lane)*12;
      *(f32x4*)(dst+0) = acc0; *(f32x4*)(dst+4) = acc1; *(f32x4*)(dst+8) = acc2;
    }
    __syncthreads();                                     // (3) Xch ready
    f32x4 hnv{};
    if (!half){
      const float* src = Xch + (size_t)(mf*64 + lane)*12;
      f32x4 p0 = *(const f32x4*)(src+0);
      f32x4 p1 = *(const f32x4*)(src+4);
      f32x4 p2 = *(const f32x4*)(src+8);
      int mlocal = mf*16 + (lane>>4)*4;
      #pragma unroll
      for (int j=0;j<4;j++){
        float u  = sigm(acc0[j] + p0[j] + bu_v);
        float rr = sigm(acc1[j] + p1[j] + br_v);
        float hh = tanhf(p2[j] + bh_v + rr*acc2[j]);
        float hn = (1.f-u)*hp[j] + u*hh;
        hp[j] = hn;
        hnv[j] = hn;
        Hn[(mlocal+j)*20 + (lane&15)] = (bf16)hn;
      }
    } else if (st < SS-1){   // prefetch next x A-frags during epilogue/sync window
      const bf16* g = xA + (size_t)(st+1)*DD;
      LDX(0,0); LDX(1,64); LDX(2,128); LDX(3,192); LDX(4,256); LDX(5,320); LDX(6,384); LDX(7,448);
      LDX(8,512); LDX(9,576); LDX(10,640); LDX(11,704); LDX(12,768); LDX(13,832); LDX(14,896); LDX(15,960);
    }
    __syncthreads();                                     // (4) Hn ready
    if (st < SS-1){
      // ---- publish h via returning swaps (ack), then group barrier ----
      unsigned pv = (unsigned)b2u(Hn[pm*20 + pdc*2]) | ((unsigned)b2u(Hn[pm*20 + pdc*2 + 1]) << 16);
      unsigned* pd = (st&1)? packdst0 : packdst1;
      swapG(pd, pv);
      asm volatile("s_waitcnt vmcnt(0)" ::: "memory");
      __syncthreads();                                   // (5) all publishes acked
      if (tid==0){
        unsigned v;
        int* cp = cbase + st + 1;
        asm volatile("global_atomic_add %0, %1, off sc1" :: "v"(cp), "v"(1u) : "memory");
        do { __builtin_amdgcn_s_sleep(2);
             asm volatile("global_load_dword %0, %1, off sc0 sc1\n\ts_waitcnt vmcnt(0)" : "=v"(v) : "v"(cp) : "memory");
        } while (v < WPG);
      }
      __syncthreads();                                   // (6) barrier done
    }
    // ---- deferred output stores (drain under next step's A-load wait) ----
    if (!half){
      int mlocal = mf*16 + (lane>>4)*4;
      #pragma unroll
      for (int j=0;j<4;j++){
        int m = m0 + mlocal + j;
        out[((size_t)m*SS + st)*DD + dcol] = hnv[j];
        if (st == SS-1) hlast[(size_t)m*DD + dcol] = hnv[j];
      }
    }
  }
}

extern "C" void kernel_launch(void* const* d_in, const int* in_sizes, int n_in,
                              void* d_out, int out_size, void* d_ws, size_t ws_size,
                              hipStream_t stream){
  const float* x   = (const float*)d_in[0];
  // d_in[1] = item (unused: softmax over length-1 axis == 1)
  const float* h0  = (const float*)d_in[2];
  const float* Wu  = (const float*)d_in[3];
  const float* Uu  = (const float*)d_in[4];
  const float* bu  = (const float*)d_in[5];
  const float* Wr  = (const float*)d_in[6];
  const float* Ur  = (const float*)d_in[7];
  const float* br  = (const float*)d_in[8];
  const float* Wh  = (const float*)d_in[9];
  const float* Uh  = (const float*)d_in[10];
  const float* bh  = (const float*)d_in[11];
  // d_in[12] = Wa (unused)
  float* out   = (float*)d_out;
  float* hlast = out + (size_t)MTOT*DD;

  char* ws = (char*)d_ws;
  bf16* xb  = (bf16*)(ws);                 // 32 MB
  bf16* hb0 = (bf16*)(ws + 0x2000000);     // 256 KB
  bf16* hb1 = (bf16*)(ws + 0x2040000);     // 256 KB
  int*  cnt = (int*)(ws + 0x2080000);      // 8*129 ints

  k_cvtx<<<dim3(2048), dim3(256), 0, stream>>>(x, xb);
  k_zero<<<dim3(1), dim3(NTHR), 0, stream>>>(cnt, GROUPS*SLOTS);
  k_main<<<dim3(NWG), dim3(NTHR), 16384, stream>>>(
      xb, h0, Wu, Uu, bu, Wr, Ur, br, Wh, Uh, bh, hb0, hb1, cnt, out, hlast);
}